// Round 2
// baseline (3315.159 us; speedup 1.0000x reference)
//
#include <hip/hip_runtime.h>

// ECGLSTM: B=256, T=5000, input_size=1, H=64, fused FC(64->128)+ReLU.
// One block (256 thr = 4 waves) per batch element. Thread tid owns gate tid
// (W_hh row tid in VGPRs). h and c are REPLICATED per wave in registers:
// lane j of every wave holds h[j], c[j] (bitwise identical across waves,
// since all waves apply identical ops to identical LDS gate values).
// Dot product reads h via v_readlane (no LDS latency). Elementwise update is
// computed redundantly by all 4 waves (no single-wave serial phase).
// Cross-wave traffic = gates only: 1 LDS write + 4 conflict-free LDS reads +
// ONE barrier per step (double-buffered gate array removes the WAR barrier;
// the barrier's lgkmcnt drain makes two buffers sufficient).

#define LSTM_H 64
#define LSTM_T 5000
#define LSTM_B 256

__device__ __forceinline__ float fast_rcp(float v) {
    return __builtin_amdgcn_rcpf(v);
}

__device__ __forceinline__ float rl(float v, int lane) {
    return __int_as_float(__builtin_amdgcn_readlane(__float_as_int(v), lane));
}

__global__ __launch_bounds__(256) void ECGLSTM_lstm_fused(
    const float* __restrict__ x,      // [B, T]
    const float* __restrict__ W_ih,   // [4H, 1]
    const float* __restrict__ W_hh,   // [4H, H]
    const float* __restrict__ b_ih,   // [4H]
    const float* __restrict__ b_hh,   // [4H]
    const float* __restrict__ W_fc,   // [128, H]
    const float* __restrict__ b_fc,   // [128]
    float* __restrict__ out)          // [B, 128]
{
    const int tid  = threadIdx.x;     // gate index 0..255
    const int lane = tid & 63;        // hidden unit this thread tracks
    const int b    = blockIdx.x;

    __shared__ float gates[2][4 * LSTM_H];   // double-buffered gate exchange
    __shared__ float h_lds[LSTM_H];          // epilogue only

    // W_hh row `tid` -> registers
    float w[LSTM_H];
    {
        const float4* wrow = reinterpret_cast<const float4*>(W_hh + tid * LSTM_H);
        #pragma unroll
        for (int i = 0; i < LSTM_H / 4; ++i) {
            float4 v = wrow[i];
            w[4*i+0] = v.x; w[4*i+1] = v.y; w[4*i+2] = v.z; w[4*i+3] = v.w;
        }
    }
    const float wih  = W_ih[tid];
    const float bias = b_ih[tid] + b_hh[tid];
    const bool  is_tanh = ((tid >> 6) == 2);   // wave-uniform branch

    float h = 0.0f;   // replicated: lane j holds h[j] in every wave
    float c = 0.0f;   // replicated: lane j holds c[j] in every wave

    const float* xb = x + b * LSTM_T;

    for (int base = 0; base < LSTM_T; base += 64) {
        const int rem = LSTM_T - base;
        const int nt  = rem < 64 ? rem : 64;
        // 64 timesteps of x into one register, broadcast later via readlane
        const float xreg = (lane < nt) ? xb[base + lane] : 0.0f;

        for (int tt = 0; tt < nt; ++tt) {
            const int p = tt & 1;             // 64-even chunks keep parity alternating
            const float xv = rl(xreg, tt);    // uniform lane select (SGPR)

            // gate_tid = bias + x*wih + sum_k h[k]*W_hh[tid][k], h via readlane
            float a0 = 0.f, a1 = 0.f, a2 = 0.f, a3 = 0.f;
            #pragma unroll
            for (int k = 0; k < LSTM_H; k += 4) {
                a0 = fmaf(rl(h, k + 0), w[k + 0], a0);
                a1 = fmaf(rl(h, k + 1), w[k + 1], a1);
                a2 = fmaf(rl(h, k + 2), w[k + 2], a2);
                a3 = fmaf(rl(h, k + 3), w[k + 3], a3);
            }
            float g = fmaf(xv, wih, bias) + ((a0 + a1) + (a2 + a3));

            float act;
            if (is_tanh) {
                float e = __expf(2.0f * g);           // tanh(g) = 1 - 2/(e^2g+1)
                act = 1.0f - 2.0f * fast_rcp(e + 1.0f);
            } else {
                float e = __expf(-g);                 // sigmoid
                act = fast_rcp(1.0f + e);
            }
            gates[p][tid] = act;
            __syncthreads();                          // ONE barrier per step

            // Replicated elementwise update in ALL waves (identical results)
            const float ig = gates[p][lane];
            const float fg = gates[p][LSTM_H + lane];
            const float gg = gates[p][2 * LSTM_H + lane];
            const float og = gates[p][3 * LSTM_H + lane];
            c = fmaf(fg, c, ig * gg);
            float e  = __expf(2.0f * c);
            float th = 1.0f - 2.0f * fast_rcp(e + 1.0f);
            h = og * th;
        }
    }

    // Epilogue: FC(64->128) + ReLU. Stage h once through LDS.
    if (tid < LSTM_H) h_lds[tid] = h;   // wave 0's copy (identical in all waves)
    __syncthreads();

    if (tid < 128) {
        float s = b_fc[tid];
        const float4* wf = reinterpret_cast<const float4*>(W_fc + tid * LSTM_H);
        const float4* h4 = reinterpret_cast<const float4*>(h_lds);
        #pragma unroll
        for (int i = 0; i < LSTM_H / 4; ++i) {
            float4 wv = wf[i];
            float4 hv = h4[i];
            s = fmaf(hv.x, wv.x, s);
            s = fmaf(hv.y, wv.y, s);
            s = fmaf(hv.z, wv.z, s);
            s = fmaf(hv.w, wv.w, s);
        }
        out[b * 128 + tid] = fmaxf(s, 0.0f);
    }
}

extern "C" void kernel_launch(void* const* d_in, const int* in_sizes, int n_in,
                              void* d_out, int out_size, void* d_ws, size_t ws_size,
                              hipStream_t stream) {
    const float* x    = (const float*)d_in[0];
    const float* W_ih = (const float*)d_in[1];
    const float* W_hh = (const float*)d_in[2];
    const float* b_ih = (const float*)d_in[3];
    const float* b_hh = (const float*)d_in[4];
    const float* W_fc = (const float*)d_in[5];
    const float* b_fc = (const float*)d_in[6];
    float* out = (float*)d_out;

    ECGLSTM_lstm_fused<<<LSTM_B, 256, 0, stream>>>(
        x, W_ih, W_hh, b_ih, b_hh, W_fc, b_fc, out);
}